// Round 1
// baseline (519.138 us; speedup 1.0000x reference)
//
#include <hip/hip_runtime.h>

// StyleGAN 3D upsample x2, k=[1,4,6,4,1]/16*2 per axis, fused polyphase:
//   even: o[2i]   = 0.5*(x[i-1]+x[i])
//   odd : o[2i+1] = 0.125*x[i-1] + 0.75*x[i] + 0.125*x[i+1]
// Input fp32 [4,32,48,48,48], output fp32 [4,32,96,96,96].
//
// v2: full-W blocks. 24 threads along W, each owning 2 input columns ->
// 4 consecutive output floats -> float4 stores (16 B/lane). A wave's store
// covers ~2.7 complete 384 B output rows (vs 4x 128 B fragments before).

#define IN_D 48
#define IN_H 48
#define IN_W 48
#define NC   128             // N*C = 4*32
#define TD   8               // input tile depth per block
#define TH   16              // input tile height per block
#define NTX  24              // threads along W; each covers 2 input cols
#define NTHREADS (NTX * TH)  // 384 = 6 waves
#define LZ (TD + 2)          // 10 (D halo)
#define LY (TH + 2)          // 18 (H halo)
#define LX (IN_W + 2)        // 50 (W halo; halo cols are always zero)
#define LXP (LX + 1)         // 51 padded row stride (odd -> bank spread)

__device__ __forceinline__ float4 f4_even(float4 a, float4 b) {
    return make_float4(0.5f * (a.x + b.x), 0.5f * (a.y + b.y),
                       0.5f * (a.z + b.z), 0.5f * (a.w + b.w));
}
__device__ __forceinline__ float4 f4_odd(float4 a, float4 b, float4 c) {
    return make_float4(0.125f * (a.x + c.x) + 0.75f * b.x,
                       0.125f * (a.y + c.y) + 0.75f * b.y,
                       0.125f * (a.z + c.z) + 0.75f * b.z,
                       0.125f * (a.w + c.w) + 0.75f * b.w);
}

struct Q { float4 E, O; };   // h-even / h-odd row of 4 W-outputs

__global__ __launch_bounds__(NTHREADS)
void upfir3d_kernel(const float* __restrict__ in,
                    float* __restrict__ out) {
    __shared__ float lds[LZ * LY * LXP];   // 10*18*51*4 = 36720 B

    const int tx = threadIdx.x;            // 0..23
    const int ty = threadIdx.y;            // 0..15
    const int bh = blockIdx.x;             // 0..2
    const int dz = blockIdx.y;             // 0..5
    const int nc = blockIdx.z;             // 0..127

    const int ih0 = bh * TH;
    const int id0 = dz * TD;
    const size_t in_base = (size_t)nc * (IN_D * IN_H * IN_W);

    // ---- stage halo tile into LDS, zero outside input bounds ----
    const int tid = ty * NTX + tx;
    for (int idx = tid; idx < LZ * LY * LX; idx += NTHREADS) {
        int z   = idx / (LY * LX);
        int rem = idx - z * (LY * LX);
        int y   = rem / LX;
        int xx  = rem - y * LX;
        int gd = id0 - 1 + z;
        int gh = ih0 - 1 + y;
        int gw = xx - 1;                   // block spans full W
        float v = 0.0f;
        if ((unsigned)gd < (unsigned)IN_D && (unsigned)gh < (unsigned)IN_H &&
            (unsigned)gw < (unsigned)IN_W) {
            v = in[in_base + ((size_t)gd * IN_H + gh) * IN_W + gw];
        }
        lds[(z * LY + y) * LXP + xx] = v;
    }
    __syncthreads();

    // ---- per-thread: 2 input columns (ic0=2tx, ic1=2tx+1), slide along D ----
    const int ly = ty + 1;
    const int c0 = 2 * tx;                 // LDS col of x[ic0-1]

    // WH-combined partials for one LDS layer z:
    //   E = row oh   (h-even): 4 W-outputs {wE0, wO0, wE1, wO1}
    //   O = row oh+1 (h-odd)
    auto whpart = [&](int z) -> Q {
        const float* p = &lds[(z * LY + (ly - 1)) * LXP + c0];
        float4 r[3];
#pragma unroll
        for (int dy = 0; dy < 3; ++dy) {
            float v0 = p[dy * LXP + 0];
            float v1 = p[dy * LXP + 1];
            float v2 = p[dy * LXP + 2];
            float v3 = p[dy * LXP + 3];
            r[dy].x = 0.5f * (v0 + v1);                    // out 4tx   (w even)
            r[dy].y = 0.125f * (v0 + v2) + 0.75f * v1;     // out 4tx+1 (w odd)
            r[dy].z = 0.5f * (v1 + v2);                    // out 4tx+2 (w even)
            r[dy].w = 0.125f * (v1 + v3) + 0.75f * v2;     // out 4tx+3 (w odd)
        }
        Q q;
        q.E = f4_even(r[0], r[1]);
        q.O = f4_odd(r[0], r[1], r[2]);
        return q;
    };

    Q qm = whpart(0);        // layer id0-1
    Q qc = whpart(1);        // layer id0

    const int OD = 2 * IN_D, OH = 2 * IN_H, OW = 2 * IN_W;
    const int ow = 4 * tx;                 // 16B-aligned float4 slot
    const int oh = 2 * (ih0 + ty);
    float* ob = out + (size_t)nc * OD * OH * OW;

#pragma unroll
    for (int d = 0; d < TD; ++d) {
        Q qp = whpart(d + 2);              // layer id0+d+1
        const int od = 2 * (id0 + d);

        size_t b0 = ((size_t)od * OH + oh) * OW + ow;          // d-even plane
        *reinterpret_cast<float4*>(ob + b0)      = f4_even(qm.E, qc.E);
        *reinterpret_cast<float4*>(ob + b0 + OW) = f4_even(qm.O, qc.O);

        size_t b1 = b0 + (size_t)OH * OW;                      // d-odd plane
        *reinterpret_cast<float4*>(ob + b1)      = f4_odd(qm.E, qc.E, qp.E);
        *reinterpret_cast<float4*>(ob + b1 + OW) = f4_odd(qm.O, qc.O, qp.O);

        qm = qc;
        qc = qp;
    }
}

extern "C" void kernel_launch(void* const* d_in, const int* in_sizes, int n_in,
                              void* d_out, int out_size, void* d_ws, size_t ws_size,
                              hipStream_t stream) {
    const float* x = (const float*)d_in[0];
    float* out = (float*)d_out;

    dim3 grid(IN_H / TH, IN_D / TD, NC);   // (3, 6, 128) = 2304 blocks
    dim3 block(NTX, TH, 1);                // (24, 16) = 384 threads
    upfir3d_kernel<<<grid, block, 0, stream>>>(x, out);
}

// Round 2
// 483.828 us; speedup vs baseline: 1.0730x; 1.0730x over previous
//
#include <hip/hip_runtime.h>

// StyleGAN 3D upsample x2, k=[1,4,6,4,1]/16*2 per axis, fused polyphase:
//   even: o[2i]   = 0.5*(x[i-1]+x[i])
//   odd : o[2i+1] = 0.125*x[i-1] + 0.75*x[i] + 0.125*x[i+1]
// Input fp32 [4,32,48,48,48], output fp32 [4,32,96,96,96].
//
// v3: v2's full-W float4-store structure, plus:
//  - float4-vectorized LDS staging (4.5 iters vs 23.4 scalar iters; no W
//    bounds checks; ~1KB contiguous global reads per wave-inst)
//  - TD 8->6: LDS 36.7->29.4 KB -> 5 blocks/CU (30 waves), 3072 blocks

#define IN_D 48
#define IN_H 48
#define IN_W 48
#define NC   128             // N*C = 4*32
#define TD   6               // input tile depth per block
#define TH   16              // input tile height per block
#define NTX  24              // threads along W; each covers 2 input cols
#define NTHREADS (NTX * TH)  // 384 = 6 waves
#define LZ (TD + 2)          // 8  (D halo)
#define LY (TH + 2)          // 18 (H halo)
#define LX (IN_W + 2)        // 50 (W halo; halo cols are always zero)
#define LXP (LX + 1)         // 51 padded row stride
#define NROWS (LZ * LY)      // 144 staged rows

__device__ __forceinline__ float4 f4_even(float4 a, float4 b) {
    return make_float4(0.5f * (a.x + b.x), 0.5f * (a.y + b.y),
                       0.5f * (a.z + b.z), 0.5f * (a.w + b.w));
}
__device__ __forceinline__ float4 f4_odd(float4 a, float4 b, float4 c) {
    return make_float4(0.125f * (a.x + c.x) + 0.75f * b.x,
                       0.125f * (a.y + c.y) + 0.75f * b.y,
                       0.125f * (a.z + c.z) + 0.75f * b.z,
                       0.125f * (a.w + c.w) + 0.75f * b.w);
}

struct Q { float4 E, O; };   // h-even / h-odd row of 4 W-outputs

__global__ __launch_bounds__(NTHREADS)
void upfir3d_kernel(const float* __restrict__ in,
                    float* __restrict__ out) {
    __shared__ float lds[NROWS * LXP];     // 144*51*4 = 29376 B

    const int tx = threadIdx.x;            // 0..23
    const int ty = threadIdx.y;            // 0..15
    const int bh = blockIdx.x;             // 0..2
    const int dz = blockIdx.y;             // 0..7
    const int nc = blockIdx.z;             // 0..127

    const int ih0 = bh * TH;
    const int id0 = dz * TD;
    const size_t in_base = (size_t)nc * (IN_D * IN_H * IN_W);

    const int tid = ty * NTX + tx;

    // ---- zero halo columns (col 0 and col 49) ----
    if (tid < 2 * NROWS) {
        int row = tid >> 1;
        int col = (tid & 1) ? (LX - 1) : 0;
        lds[row * LXP + col] = 0.0f;
    }

    // ---- stage interior: 12 float4 per (z,y) row, zero outside D/H bounds ----
    {
        const int q = tid % 12;            // float4 slot within the row
        const int r = tid / 12;            // starting row; stride 32
        for (int row = r; row < NROWS; row += NTHREADS / 12) {
            int z  = row / LY;
            int y  = row - z * LY;
            int gd = id0 - 1 + z;
            int gh = ih0 - 1 + y;
            float4 v = make_float4(0.f, 0.f, 0.f, 0.f);
            if ((unsigned)gd < (unsigned)IN_D && (unsigned)gh < (unsigned)IN_H) {
                v = *reinterpret_cast<const float4*>(
                        in + in_base + ((size_t)gd * IN_H + gh) * IN_W + 4 * q);
            }
            float* dst = &lds[row * LXP + 1 + 4 * q];
            dst[0] = v.x; dst[1] = v.y; dst[2] = v.z; dst[3] = v.w;
        }
    }
    __syncthreads();

    // ---- per-thread: 2 input columns (2tx, 2tx+1), slide along D ----
    const int ly = ty + 1;
    const int c0 = 2 * tx;                 // LDS col of x[2tx-1]

    // WH-combined partials for one LDS layer z:
    //   E = row oh   (h-even): 4 W-outputs {wE0, wO0, wE1, wO1}
    //   O = row oh+1 (h-odd)
    auto whpart = [&](int z) -> Q {
        const float* p = &lds[(z * LY + (ly - 1)) * LXP + c0];
        float4 r[3];
#pragma unroll
        for (int dy = 0; dy < 3; ++dy) {
            float v0 = p[dy * LXP + 0];
            float v1 = p[dy * LXP + 1];
            float v2 = p[dy * LXP + 2];
            float v3 = p[dy * LXP + 3];
            r[dy].x = 0.5f * (v0 + v1);                    // out 4tx   (w even)
            r[dy].y = 0.125f * (v0 + v2) + 0.75f * v1;     // out 4tx+1 (w odd)
            r[dy].z = 0.5f * (v1 + v2);                    // out 4tx+2 (w even)
            r[dy].w = 0.125f * (v1 + v3) + 0.75f * v2;     // out 4tx+3 (w odd)
        }
        Q q;
        q.E = f4_even(r[0], r[1]);
        q.O = f4_odd(r[0], r[1], r[2]);
        return q;
    };

    Q qm = whpart(0);        // layer id0-1
    Q qc = whpart(1);        // layer id0

    const int OD = 2 * IN_D, OH = 2 * IN_H, OW = 2 * IN_W;
    const int ow = 4 * tx;                 // 16B-aligned float4 slot
    const int oh = 2 * (ih0 + ty);
    float* ob = out + (size_t)nc * OD * OH * OW;

#pragma unroll
    for (int d = 0; d < TD; ++d) {
        Q qp = whpart(d + 2);              // layer id0+d+1
        const int od = 2 * (id0 + d);

        size_t b0 = ((size_t)od * OH + oh) * OW + ow;          // d-even plane
        *reinterpret_cast<float4*>(ob + b0)      = f4_even(qm.E, qc.E);
        *reinterpret_cast<float4*>(ob + b0 + OW) = f4_even(qm.O, qc.O);

        size_t b1 = b0 + (size_t)OH * OW;                      // d-odd plane
        *reinterpret_cast<float4*>(ob + b1)      = f4_odd(qm.E, qc.E, qp.E);
        *reinterpret_cast<float4*>(ob + b1 + OW) = f4_odd(qm.O, qc.O, qp.O);

        qm = qc;
        qc = qp;
    }
}

extern "C" void kernel_launch(void* const* d_in, const int* in_sizes, int n_in,
                              void* d_out, int out_size, void* d_ws, size_t ws_size,
                              hipStream_t stream) {
    const float* x = (const float*)d_in[0];
    float* out = (float*)d_out;

    dim3 grid(IN_H / TH, IN_D / TD, NC);   // (3, 8, 128) = 3072 blocks
    dim3 block(NTX, TH, 1);                // (24, 16) = 384 threads
    upfir3d_kernel<<<grid, block, 0, stream>>>(x, out);
}